// Round 1
// baseline (706.422 us; speedup 1.0000x reference)
//
#include <hip/hip_runtime.h>
#include <math.h>

#define TWO_PI_256 0.024543692606170259678f  // 2*pi/256

// ---------------- Pass 1: partial DFT over w ----------------
// Xw[bc][kx][h] = sum_w x[bc][h][w] * e^{-2pi i kx w/256}, kx in [0,16)
__global__ __launch_bounds__(128) void k_dftw(const float* __restrict__ x,
                                              float2* __restrict__ Xw) {
    const int tid = threadIdx.x;
    const int bc = blockIdx.x >> 3;          // 1024 planes
    const int h0 = (blockIdx.x & 7) << 5;    // 8 chunks of 32 rows
    __shared__ float xs[32][258];
    __shared__ float2 tw[256];
    {
        int t = tid;
        float s, c;
        sincosf((float)t * TWO_PI_256, &s, &c);
        tw[t] = make_float2(c, s);
        t += 128;
        sincosf((float)t * TWO_PI_256, &s, &c);
        tw[t] = make_float2(c, s);
    }
    const float2* xp = (const float2*)(x + ((size_t)bc << 16) + ((size_t)h0 << 8));
    #pragma unroll
    for (int k = 0; k < 32; ++k) {
        int f2 = tid + (k << 7);             // 0..4095 float2 units
        int r = f2 >> 7, w2 = (f2 & 127) << 1;
        *(float2*)&xs[r][w2] = xp[f2];
    }
    __syncthreads();
    const int kx = tid >> 3;                 // 0..15
    const int hb = tid & 7;                  // rows hb + 8r
    float ar[4] = {0.f, 0.f, 0.f, 0.f}, ai[4] = {0.f, 0.f, 0.f, 0.f};
    int t = 0;
    #pragma unroll 2
    for (int w = 0; w < 256; ++w) {
        float2 cs = tw[t];
        #pragma unroll
        for (int r = 0; r < 4; ++r) {
            float xv = xs[hb + (r << 3)][w];
            ar[r] = fmaf(xv, cs.x, ar[r]);
            ai[r] = fmaf(xv, -cs.y, ai[r]);
        }
        t = (t + kx) & 255;
    }
    float2* op = Xw + ((size_t)bc << 12) + (kx << 8) + h0 + hb;
    #pragma unroll
    for (int r = 0; r < 4; ++r) op[r << 3] = make_float2(ar[r], ai[r]);
}

// ---------------- Pass 2: DFT over h at 32 ky values ----------------
// XhT[mode][b*64+c], mode = kyIdx*16+kx; kyIdx<16 -> ky=kyIdx, else ky=224+kyIdx
__global__ __launch_bounds__(256) void k_dfth(const float2* __restrict__ Xw,
                                              float2* __restrict__ XhT) {
    const int tid = threadIdx.x;
    const int bc = blockIdx.x;
    __shared__ float2 xw[16][258];
    __shared__ float2 tw[256];
    {
        float s, c;
        sincosf((float)tid * TWO_PI_256, &s, &c);
        tw[tid] = make_float2(c, s);
    }
    const float2* src = Xw + ((size_t)bc << 12);
    #pragma unroll
    for (int k = 0; k < 16; ++k) {
        int f = tid + (k << 8);
        xw[f >> 8][f & 255] = src[f];
    }
    __syncthreads();
    const int kx = tid & 15, slot = tid >> 4;
    const int physb = 240 + slot;
    float tr = 0.f, ti = 0.f, br = 0.f, bi = 0.f;
    int t1 = 0, t2 = 0;
    for (int h = 0; h < 256; ++h) {
        float2 v = xw[kx][h];
        float2 cA = tw[t1];
        float2 cB = tw[t2];
        tr = fmaf(v.x, cA.x, fmaf(v.y, cA.y, tr));
        ti = fmaf(v.y, cA.x, fmaf(-v.x, cA.y, ti));
        br = fmaf(v.x, cB.x, fmaf(v.y, cB.y, br));
        bi = fmaf(v.y, cB.x, fmaf(-v.x, cB.y, bi));
        t1 = (t1 + slot) & 255;
        t2 = (t2 + physb) & 255;
    }
    XhT[(size_t)(((slot << 4) + kx) << 10) + bc] = make_float2(tr, ti);
    XhT[(size_t)((((16 + slot) << 4) + kx) << 10) + bc] = make_float2(br, bi);
}

// ---------------- Pass 3: per-mode 64x64 complex channel mix ----------------
// S[b][o][mode] = sum_i XhT[mode][b*64+i] * W[i][o][mode] / 65536
__global__ __launch_bounds__(256) void k_modes(const float2* __restrict__ XhT,
        const float* __restrict__ w1r, const float* __restrict__ w1i,
        const float* __restrict__ w2r, const float* __restrict__ w2i,
        float2* __restrict__ S) {
    const int tid = threadIdx.x;
    const int mode = blockIdx.x;             // 0..511
    const int kyIdx = mode >> 4, kx = mode & 15;
    const int xy = ((kyIdx & 15) << 4) + kx;
    const float* __restrict__ wr = (kyIdx < 16) ? w1r : w2r;
    const float* __restrict__ wi = (kyIdx < 16) ? w1i : w2i;
    __shared__ float2 xin[16][65];
    __shared__ float2 wlds[64][64];
    const float2* xsrc = XhT + ((size_t)mode << 10);
    #pragma unroll
    for (int k = 0; k < 4; ++k) {
        int f = tid + (k << 8);
        xin[f >> 6][f & 63] = xsrc[f];
    }
    const float sc = 1.52587890625e-05f;     // 1/65536 (irfft2 normalization)
    #pragma unroll
    for (int k = 0; k < 16; ++k) {
        int e = tid + (k << 8);              // i*64+o
        size_t a = ((size_t)e << 8) + xy;
        wlds[e >> 6][e & 63] = make_float2(wr[a] * sc, wi[a] * sc);
    }
    __syncthreads();
    const int b = tid >> 4, o0 = tid & 15;
    float2 acc[4] = {};
    for (int i = 0; i < 64; ++i) {
        float2 a = xin[b][i];
        #pragma unroll
        for (int k = 0; k < 4; ++k) {
            float2 wv = wlds[i][o0 + (k << 4)];
            acc[k].x = fmaf(a.x, wv.x, fmaf(-a.y, wv.y, acc[k].x));
            acc[k].y = fmaf(a.x, wv.y, fmaf(a.y, wv.x, acc[k].y));
        }
    }
    float2* sp = S + ((size_t)((b << 6) + o0) << 9) + mode;
    #pragma unroll
    for (int k = 0; k < 4; ++k) sp[(size_t)(k << 13)] = acc[k];  // o += 16 -> 16*512
}

// ---------------- Pass 4: inverse DFT over h ----------------
// Y[bo][h][kx] = sum_ky S[bo][ky][kx] * e^{+2pi i phys(ky) h/256}
__global__ __launch_bounds__(256) void k_invh(const float2* __restrict__ S,
                                              float2* __restrict__ Y) {
    const int tid = threadIdx.x;
    const int bo = blockIdx.x;               // b*64+o
    __shared__ float2 sl[32][16];
    __shared__ float2 tw[256];
    {
        float s, c;
        sincosf((float)tid * TWO_PI_256, &s, &c);
        tw[tid] = make_float2(c, s);
    }
    ((float2*)sl)[tid] = S[((size_t)bo << 9) + tid];
    ((float2*)sl)[tid + 256] = S[((size_t)bo << 9) + tid + 256];
    __syncthreads();
    const int kx = tid & 15, hs = tid >> 4;
    float2* yp = Y + ((size_t)bo << 12) + kx;
    for (int j = 0; j < 16; ++j) {
        const int h = (hs << 4) + j;
        float ar = 0.f, ai = 0.f;
        #pragma unroll
        for (int ky = 0; ky < 32; ++ky) {
            const int phys = (ky < 16) ? ky : (224 + ky);
            const int t = (phys * h) & 255;
            float2 s = sl[ky][kx];
            float2 cs = tw[t];
            ar = fmaf(s.x, cs.x, fmaf(-s.y, cs.y, ar));
            ai = fmaf(s.y, cs.x, fmaf(s.x, cs.y, ai));
        }
        yp[(size_t)h << 4] = make_float2(ar, ai);
    }
}

// ---------------- Pass 5: inverse DFT over w + 1x1 conv + bias + exact GELU ----------------
__global__ __launch_bounds__(256) void k_final(const float* __restrict__ x,
        const float* __restrict__ Wc, const float* __restrict__ bcv,
        const float2* __restrict__ Y, float* __restrict__ out) {
    const int tid = threadIdx.x;
    const int blk = blockIdx.x;
    const int wh = blk & 1, h = (blk >> 1) & 255, b = blk >> 9;
    __shared__ float xs[64][132];
    __shared__ float wct[64][68];
    __shared__ float ytr[16][68], yti[16][68];
    __shared__ float2 twp[272];              // idx(t) = t + (t>>4): bank-swizzled
    __shared__ float bcs[64];
    {
        float s, c;
        sincosf((float)tid * TWO_PI_256, &s, &c);
        twp[tid + (tid >> 4)] = make_float2(c, s);
        if (tid < 64) bcs[tid] = bcv[tid];
    }
    {
        const float* xp = x + ((size_t)b << 22) + ((size_t)h << 8) + (wh << 7);
        #pragma unroll
        for (int k = 0; k < 8; ++k) {
            int f4 = tid + (k << 8);         // 0..2047 float4 units
            int c = f4 >> 5, w4 = (f4 & 31) << 2;
            float4 v = *(const float4*)(xp + ((size_t)c << 16) + w4);
            *(float4*)&xs[c][w4] = v;
        }
    }
    #pragma unroll
    for (int k = 0; k < 16; ++k) {
        int f = tid + (k << 8);              // f = o*64+c
        wct[f & 63][f >> 6] = Wc[f];
    }
    #pragma unroll
    for (int k = 0; k < 4; ++k) {
        int f = tid + (k << 8);              // 0..1023
        int o = f >> 4, kxi = f & 15;
        float2 v = Y[((size_t)((b << 6) + o) << 12) + (h << 4) + kxi];
        float scl = kxi ? 2.0f : 1.0f;       // irfft C2R: Re-only for kx=0, 2x otherwise
        ytr[kxi][o] = v.x * scl;
        yti[kxi][o] = v.y * scl;
    }
    __syncthreads();
    const int ws = tid & 31, og = tid >> 5;  // o-tile = og*8..+7; w = wh*128 + 2*ws (+1,+64,+65)
    float a[8][4];
    #pragma unroll
    for (int k = 0; k < 8; ++k) {
        #pragma unroll
        for (int j = 0; j < 4; ++j) a[k][j] = 0.f;
    }
    for (int c = 0; c < 64; ++c) {
        float2 xv0 = *(const float2*)&xs[c][ws << 1];
        float2 xv1 = *(const float2*)&xs[c][(ws << 1) + 64];
        float4 wv0 = *(const float4*)&wct[c][og << 3];
        float4 wv1 = *(const float4*)&wct[c][(og << 3) + 4];
        const float wv[8] = {wv0.x, wv0.y, wv0.z, wv0.w, wv1.x, wv1.y, wv1.z, wv1.w};
        #pragma unroll
        for (int k = 0; k < 8; ++k) {
            a[k][0] = fmaf(wv[k], xv0.x, a[k][0]);
            a[k][1] = fmaf(wv[k], xv0.y, a[k][1]);
            a[k][2] = fmaf(wv[k], xv1.x, a[k][2]);
            a[k][3] = fmaf(wv[k], xv1.y, a[k][3]);
        }
    }
    const int wbase = (wh << 7) + (ws << 1);
    #pragma unroll
    for (int kx = 0; kx < 16; ++kx) {
        float4 yr0 = *(const float4*)&ytr[kx][og << 3];
        float4 yr1 = *(const float4*)&ytr[kx][(og << 3) + 4];
        float4 yi0 = *(const float4*)&yti[kx][og << 3];
        float4 yi1 = *(const float4*)&yti[kx][(og << 3) + 4];
        const float yrv[8] = {yr0.x, yr0.y, yr0.z, yr0.w, yr1.x, yr1.y, yr1.z, yr1.w};
        const float yiv[8] = {yi0.x, yi0.y, yi0.z, yi0.w, yi1.x, yi1.y, yi1.z, yi1.w};
        int t0 = (kx * wbase) & 255;
        int t1 = (t0 + kx) & 255;
        int t2 = (t0 + ((kx << 6) & 255)) & 255;
        int t3 = (t2 + kx) & 255;
        float2 c0 = twp[t0 + (t0 >> 4)];
        float2 c1 = twp[t1 + (t1 >> 4)];
        float2 c2 = twp[t2 + (t2 >> 4)];
        float2 c3 = twp[t3 + (t3 >> 4)];
        #pragma unroll
        for (int k = 0; k < 8; ++k) {
            a[k][0] = fmaf(yrv[k], c0.x, fmaf(-yiv[k], c0.y, a[k][0]));
            a[k][1] = fmaf(yrv[k], c1.x, fmaf(-yiv[k], c1.y, a[k][1]));
            a[k][2] = fmaf(yrv[k], c2.x, fmaf(-yiv[k], c2.y, a[k][2]));
            a[k][3] = fmaf(yrv[k], c3.x, fmaf(-yiv[k], c3.y, a[k][3]));
        }
    }
    float* op = out + ((size_t)b << 22) + ((size_t)(og << 3) << 16)
                    + ((size_t)h << 8) + (wh << 7) + (ws << 1);
    #pragma unroll
    for (int k = 0; k < 8; ++k) {
        const float bias = bcs[(og << 3) + k];
        float2 r0, r1;
        float v = a[k][0] + bias;
        r0.x = 0.5f * v * (1.0f + erff(v * 0.70710678118654752440f));
        v = a[k][1] + bias;
        r0.y = 0.5f * v * (1.0f + erff(v * 0.70710678118654752440f));
        v = a[k][2] + bias;
        r1.x = 0.5f * v * (1.0f + erff(v * 0.70710678118654752440f));
        v = a[k][3] + bias;
        r1.y = 0.5f * v * (1.0f + erff(v * 0.70710678118654752440f));
        *(float2*)(op + ((size_t)k << 16)) = r0;
        *(float2*)(op + ((size_t)k << 16) + 64) = r1;
    }
}

extern "C" void kernel_launch(void* const* d_in, const int* in_sizes, int n_in,
                              void* d_out, int out_size, void* d_ws, size_t ws_size,
                              hipStream_t stream) {
    const float* x   = (const float*)d_in[0];
    const float* Wc  = (const float*)d_in[1];
    const float* bcv = (const float*)d_in[2];
    const float* w1r = (const float*)d_in[3];
    const float* w1i = (const float*)d_in[4];
    const float* w2r = (const float*)d_in[5];
    const float* w2i = (const float*)d_in[6];
    float* out = (float*)d_out;

    // workspace: Xw (4,194,304 f2) | Y (4,194,304 f2) | XhT (524,288 f2) | S (524,288 f2) = 75.5 MB
    float2* Xw  = (float2*)d_ws;
    float2* Y   = Xw + 4194304;
    float2* XhT = Y + 4194304;
    float2* S   = XhT + 524288;

    k_dftw <<<8192, 128, 0, stream>>>(x, Xw);
    k_dfth <<<1024, 256, 0, stream>>>(Xw, XhT);
    k_modes<<< 512, 256, 0, stream>>>(XhT, w1r, w1i, w2r, w2i, S);
    k_invh <<<1024, 256, 0, stream>>>(S, Y);
    k_final<<<8192, 256, 0, stream>>>(x, Wc, bcv, Y, out);
}

// Round 2
// 390.100 us; speedup vs baseline: 1.8109x; 1.8109x over previous
//
#include <hip/hip_runtime.h>
#include <math.h>

#define TWO_PI_256 0.024543692606170259678f  // 2*pi/256

typedef __attribute__((ext_vector_type(8))) short bf16x8;
typedef __attribute__((ext_vector_type(4))) float f32x4;

static __device__ __forceinline__ ushort bf16_rn(float a) {
    union { float f; unsigned int u; } v; v.f = a;
    unsigned int r = v.u + 0x7FFFu + ((v.u >> 16) & 1u);
    return (ushort)(r >> 16);
}
static __device__ __forceinline__ float bf16_to_f(ushort h) {
    union { unsigned int u; float f; } v; v.u = ((unsigned int)h) << 16;
    return v.f;
}
static __device__ __forceinline__ void split2(float a, ushort& hi, ushort& lo) {
    ushort h = bf16_rn(a);
    hi = h;
    lo = bf16_rn(a - bf16_to_f(h));
}

// ---------------- Pass 0: precompute bf16-split Wc and trig table T ----------------
// Wch/Wcl: [o][c] 64x64.  Tgh/Tgl: [w][kz] 256x32, kz<16: cos(2pi*kz*w/256), kz>=16: sin(2pi*(kz-16)*w/256)
__global__ __launch_bounds__(256) void k_prep(const float* __restrict__ Wc,
        ushort* __restrict__ Wch, ushort* __restrict__ Wcl,
        ushort* __restrict__ Tgh, ushort* __restrict__ Tgl) {
    int g = blockIdx.x * 256 + threadIdx.x;
    if (g < 4096) {
        ushort h, l; split2(Wc[g], h, l);
        Wch[g] = h; Wcl[g] = l;
    }
    int t = g - 4096;
    if (t >= 0 && t < 8192) {
        int w = t >> 5, kz = t & 31, kx = kz & 15;
        int ph = (w * kx) & 255;                 // exact mod-256 reduction
        float s, c; sincosf((float)ph * TWO_PI_256, &s, &c);
        float val = (kz < 16) ? c : s;
        ushort h, l; split2(val, h, l);
        Tgh[t] = h; Tgl[t] = l;
    }
}

// ---------------- Pass 1: partial DFT over w ----------------
__global__ __launch_bounds__(128) void k_dftw(const float* __restrict__ x,
                                              float2* __restrict__ Xw) {
    const int tid = threadIdx.x;
    const int bc = blockIdx.x >> 3;
    const int h0 = (blockIdx.x & 7) << 5;
    __shared__ float xs[32][258];
    __shared__ float2 tw[256];
    {
        int t = tid;
        float s, c;
        sincosf((float)t * TWO_PI_256, &s, &c);
        tw[t] = make_float2(c, s);
        t += 128;
        sincosf((float)t * TWO_PI_256, &s, &c);
        tw[t] = make_float2(c, s);
    }
    const float2* xp = (const float2*)(x + ((size_t)bc << 16) + ((size_t)h0 << 8));
    #pragma unroll
    for (int k = 0; k < 32; ++k) {
        int f2 = tid + (k << 7);
        int r = f2 >> 7, w2 = (f2 & 127) << 1;
        *(float2*)&xs[r][w2] = xp[f2];
    }
    __syncthreads();
    const int kx = tid >> 3;
    const int hb = tid & 7;
    float ar[4] = {0.f, 0.f, 0.f, 0.f}, ai[4] = {0.f, 0.f, 0.f, 0.f};
    int t = 0;
    #pragma unroll 2
    for (int w = 0; w < 256; ++w) {
        float2 cs = tw[t];
        #pragma unroll
        for (int r = 0; r < 4; ++r) {
            float xv = xs[hb + (r << 3)][w];
            ar[r] = fmaf(xv, cs.x, ar[r]);
            ai[r] = fmaf(xv, -cs.y, ai[r]);
        }
        t = (t + kx) & 255;
    }
    float2* op = Xw + ((size_t)bc << 12) + (kx << 8) + h0 + hb;
    #pragma unroll
    for (int r = 0; r < 4; ++r) op[r << 3] = make_float2(ar[r], ai[r]);
}

// ---------------- Pass 2: DFT over h at 32 ky values ----------------
__global__ __launch_bounds__(256) void k_dfth(const float2* __restrict__ Xw,
                                              float2* __restrict__ XhT) {
    const int tid = threadIdx.x;
    const int bc = blockIdx.x;
    __shared__ float2 xw[16][258];
    __shared__ float2 tw[256];
    {
        float s, c;
        sincosf((float)tid * TWO_PI_256, &s, &c);
        tw[tid] = make_float2(c, s);
    }
    const float2* src = Xw + ((size_t)bc << 12);
    #pragma unroll
    for (int k = 0; k < 16; ++k) {
        int f = tid + (k << 8);
        xw[f >> 8][f & 255] = src[f];
    }
    __syncthreads();
    const int kx = tid & 15, slot = tid >> 4;
    const int physb = 240 + slot;
    float tr = 0.f, ti = 0.f, br = 0.f, bi = 0.f;
    int t1 = 0, t2 = 0;
    for (int h = 0; h < 256; ++h) {
        float2 v = xw[kx][h];
        float2 cA = tw[t1];
        float2 cB = tw[t2];
        tr = fmaf(v.x, cA.x, fmaf(v.y, cA.y, tr));
        ti = fmaf(v.y, cA.x, fmaf(-v.x, cA.y, ti));
        br = fmaf(v.x, cB.x, fmaf(v.y, cB.y, br));
        bi = fmaf(v.y, cB.x, fmaf(-v.x, cB.y, bi));
        t1 = (t1 + slot) & 255;
        t2 = (t2 + physb) & 255;
    }
    XhT[(size_t)(((slot << 4) + kx) << 10) + bc] = make_float2(tr, ti);
    XhT[(size_t)((((16 + slot) << 4) + kx) << 10) + bc] = make_float2(br, bi);
}

// ---------------- Pass 3: per-mode 64x64 complex channel mix ----------------
__global__ __launch_bounds__(256) void k_modes(const float2* __restrict__ XhT,
        const float* __restrict__ w1r, const float* __restrict__ w1i,
        const float* __restrict__ w2r, const float* __restrict__ w2i,
        float2* __restrict__ S) {
    const int tid = threadIdx.x;
    const int mode = blockIdx.x;
    const int kyIdx = mode >> 4, kx = mode & 15;
    const int xy = ((kyIdx & 15) << 4) + kx;
    const float* __restrict__ wr = (kyIdx < 16) ? w1r : w2r;
    const float* __restrict__ wi = (kyIdx < 16) ? w1i : w2i;
    __shared__ float2 xin[16][65];
    __shared__ float2 wlds[64][64];
    const float2* xsrc = XhT + ((size_t)mode << 10);
    #pragma unroll
    for (int k = 0; k < 4; ++k) {
        int f = tid + (k << 8);
        xin[f >> 6][f & 63] = xsrc[f];
    }
    const float sc = 1.52587890625e-05f;     // 1/65536 (irfft2 normalization)
    #pragma unroll
    for (int k = 0; k < 16; ++k) {
        int e = tid + (k << 8);
        size_t a = ((size_t)e << 8) + xy;
        wlds[e >> 6][e & 63] = make_float2(wr[a] * sc, wi[a] * sc);
    }
    __syncthreads();
    const int b = tid >> 4, o0 = tid & 15;
    float2 acc[4] = {};
    for (int i = 0; i < 64; ++i) {
        float2 a = xin[b][i];
        #pragma unroll
        for (int k = 0; k < 4; ++k) {
            float2 wv = wlds[i][o0 + (k << 4)];
            acc[k].x = fmaf(a.x, wv.x, fmaf(-a.y, wv.y, acc[k].x));
            acc[k].y = fmaf(a.x, wv.y, fmaf(a.y, wv.x, acc[k].y));
        }
    }
    float2* sp = S + ((size_t)((b << 6) + o0) << 9) + mode;
    #pragma unroll
    for (int k = 0; k < 4; ++k) sp[(size_t)(k << 13)] = acc[k];
}

// ---------------- Pass 4: inverse DFT over h -> bf16-split A-matrix Z-columns ----------------
// Ah/Al layout: [(b*256+h)*64 + o][32]: cols 0..15 = Zr(kx) = scl*Re, 16..31 = Zi(kx) = -scl*Im
__global__ __launch_bounds__(256) void k_invh(const float2* __restrict__ S,
                                              ushort* __restrict__ Ah,
                                              ushort* __restrict__ Al) {
    const int tid = threadIdx.x;
    const int bo = blockIdx.x;
    const int b = bo >> 6, o = bo & 63;
    __shared__ float2 sl[32][16];
    __shared__ float2 tw[256];
    {
        float s, c;
        sincosf((float)tid * TWO_PI_256, &s, &c);
        tw[tid] = make_float2(c, s);
    }
    ((float2*)sl)[tid] = S[((size_t)bo << 9) + tid];
    ((float2*)sl)[tid + 256] = S[((size_t)bo << 9) + tid + 256];
    __syncthreads();
    const int kx = tid & 15, hs = tid >> 4;
    const float scl = kx ? 2.0f : 1.0f;
    for (int j = 0; j < 16; ++j) {
        const int h = (hs << 4) + j;
        float ar = 0.f, ai = 0.f;
        #pragma unroll
        for (int ky = 0; ky < 32; ++ky) {
            const int phys = (ky < 16) ? ky : (224 + ky);
            const int t = (phys * h) & 255;
            float2 s = sl[ky][kx];
            float2 cs = tw[t];
            ar = fmaf(s.x, cs.x, fmaf(-s.y, cs.y, ar));
            ai = fmaf(s.y, cs.x, fmaf(s.x, cs.y, ai));
        }
        size_t base = (((size_t)((b << 8) + h) << 6) + o) << 5;
        ushort hh, ll;
        split2(ar * scl, hh, ll);
        Ah[base + kx] = hh;      Al[base + kx] = ll;
        split2(-ai * scl, hh, ll);
        Ah[base + 16 + kx] = hh; Al[base + 16 + kx] = ll;
    }
}

// ---------------- Pass 5: MFMA — conv + inv-DFT-w + bias + exact GELU ----------------
// Per (b,h): C[64o x 256w] = A[64 x 96] * B[96 x 256], bf16-split (Ah*Bh + Ah*Bl + Al*Bh).
// Block: (b, 4 h-rows, 64-w quarter). B tile in LDS as Xt[w][k] with XOR-b128-block swizzle.
__global__ __launch_bounds__(256) void k_final(const float* __restrict__ x,
        const ushort* __restrict__ Wch, const ushort* __restrict__ Wcl,
        const ushort* __restrict__ Tgh, const ushort* __restrict__ Tgl,
        const ushort* __restrict__ Abh, const ushort* __restrict__ Abl,
        const float* __restrict__ bcv, float* __restrict__ out) {
    const int tid = threadIdx.x;
    const int lane = tid & 63;
    const int wv = tid >> 6;
    const int blk = blockIdx.x;
    const int wq = blk & 3, ht = (blk >> 2) & 63, b = blk >> 8;
    const int w0 = wq << 6;

    __shared__ ushort Xh[64][128];   // [w_local][k] bf16-hi, b128-block-swizzled
    __shared__ ushort Xl[64][128];   // bf16-lo

    const int l15 = lane & 15, l4 = lane >> 4;
    const int mt0 = (wv >> 1) << 1;  // wave's 2 m-tiles (o)
    const int nt0 = (wv & 1) << 1;   // wave's 2 n-tiles (w)

    // --- stage T rows (k = 64..95), h-invariant: once per block ---
    {
        int w = tid & 63, kb = tid >> 6;
        size_t g = ((size_t)(w0 + w) << 5) + (kb << 3);
        bf16x8 th = *(const bf16x8*)(Tgh + g);
        bf16x8 tl = *(const bf16x8*)(Tgl + g);
        int bidx = (8 + kb) ^ (w & 7);
        *(bf16x8*)((ushort*)&Xh[w][0] + (bidx << 3)) = th;
        *(bf16x8*)((ushort*)&Xl[w][0] + (bidx << 3)) = tl;
    }

    // --- A-frags for Wc (k-steps 0,1), constant over h: registers ---
    bf16x8 aW[2][2][2];              // [mi][ks][hi/lo]
    #pragma unroll
    for (int mi = 0; mi < 2; ++mi) {
        int o = ((mt0 + mi) << 4) + l15;
        #pragma unroll
        for (int ks = 0; ks < 2; ++ks) {
            size_t g = ((size_t)o << 6) + (ks << 5) + (l4 << 3);
            aW[mi][ks][0] = *(const bf16x8*)(Wch + g);
            aW[mi][ks][1] = *(const bf16x8*)(Wcl + g);
        }
    }
    float bias[2][4];
    #pragma unroll
    for (int mi = 0; mi < 2; ++mi)
        #pragma unroll
        for (int r = 0; r < 4; ++r)
            bias[mi][r] = bcv[((mt0 + mi) << 4) + (l4 << 2) + r];

    for (int hh = 0; hh < 4; ++hh) {
        const int h = (ht << 2) + hh;

        // --- Z A-frags for this h (k-step 2): registers from global ---
        bf16x8 aZ[2][2];             // [mi][hi/lo]
        #pragma unroll
        for (int mi = 0; mi < 2; ++mi) {
            int o = ((mt0 + mi) << 4) + l15;
            size_t g = ((((size_t)((b << 8) + h) << 6) + o) << 5) + (l4 << 3);
            aZ[mi][0] = *(const bf16x8*)(Abh + g);
            aZ[mi][1] = *(const bf16x8*)(Abl + g);
        }

        __syncthreads();             // previous iteration's B reads complete
        // --- stage x(h): transpose to Xt[w][c], bf16-split, swizzled b128 writes ---
        {
            int w = tid & 63;
            int cb0 = tid >> 6;
            #pragma unroll
            for (int i = 0; i < 2; ++i) {
                int cb = cb0 + (i << 2);          // c-octet 0..7
                const float* xp = x + (((size_t)((b << 6) + (cb << 3))) << 16)
                                    + ((size_t)h << 8) + w0 + w;
                ushort hbuf[8], lbuf[8];
                #pragma unroll
                for (int j = 0; j < 8; ++j) {
                    float v = xp[(size_t)j << 16];
                    split2(v, hbuf[j], lbuf[j]);
                }
                int bidx = cb ^ (w & 7);
                *(bf16x8*)((ushort*)&Xh[w][0] + (bidx << 3)) = *(bf16x8*)hbuf;
                *(bf16x8*)((ushort*)&Xl[w][0] + (bidx << 3)) = *(bf16x8*)lbuf;
            }
        }
        __syncthreads();

        // --- MFMA: 3 k-steps x 3 split-products x (2m x 2n) ---
        f32x4 acc[2][2];
        #pragma unroll
        for (int mi = 0; mi < 2; ++mi)
            #pragma unroll
            for (int ni = 0; ni < 2; ++ni)
                acc[mi][ni] = (f32x4){0.f, 0.f, 0.f, 0.f};

        #pragma unroll
        for (int ks = 0; ks < 3; ++ks) {
            bf16x8 bh[2], bl[2];
            #pragma unroll
            for (int ni = 0; ni < 2; ++ni) {
                int w = ((nt0 + ni) << 4) + l15;
                int bidx = ((ks << 2) + l4) ^ (w & 7);
                bh[ni] = *(const bf16x8*)((const ushort*)&Xh[w][0] + (bidx << 3));
                bl[ni] = *(const bf16x8*)((const ushort*)&Xl[w][0] + (bidx << 3));
            }
            #pragma unroll
            for (int mi = 0; mi < 2; ++mi) {
                bf16x8 ah_ = (ks < 2) ? aW[mi][ks][0] : aZ[mi][0];
                bf16x8 al_ = (ks < 2) ? aW[mi][ks][1] : aZ[mi][1];
                #pragma unroll
                for (int ni = 0; ni < 2; ++ni) {
                    acc[mi][ni] = __builtin_amdgcn_mfma_f32_16x16x32_bf16(ah_, bh[ni], acc[mi][ni], 0, 0, 0);
                    acc[mi][ni] = __builtin_amdgcn_mfma_f32_16x16x32_bf16(ah_, bl[ni], acc[mi][ni], 0, 0, 0);
                    acc[mi][ni] = __builtin_amdgcn_mfma_f32_16x16x32_bf16(al_, bh[ni], acc[mi][ni], 0, 0, 0);
                }
            }
        }

        // --- epilogue: bias + exact GELU + store (D: col=lane&15 -> w, row=(lane>>4)*4+r -> o) ---
        #pragma unroll
        for (int mi = 0; mi < 2; ++mi) {
            #pragma unroll
            for (int ni = 0; ni < 2; ++ni) {
                int wg = w0 + ((nt0 + ni) << 4) + l15;
                #pragma unroll
                for (int r = 0; r < 4; ++r) {
                    int o = ((mt0 + mi) << 4) + (l4 << 2) + r;
                    float v = acc[mi][ni][r] + bias[mi][r];
                    float gel = 0.5f * v * (1.0f + erff(v * 0.70710678118654752440f));
                    out[((size_t)((b << 6) + o) << 16) + ((size_t)h << 8) + wg] = gel;
                }
            }
        }
    }
}

extern "C" void kernel_launch(void* const* d_in, const int* in_sizes, int n_in,
                              void* d_out, int out_size, void* d_ws, size_t ws_size,
                              hipStream_t stream) {
    const float* x   = (const float*)d_in[0];
    const float* Wc  = (const float*)d_in[1];
    const float* bcv = (const float*)d_in[2];
    const float* w1r = (const float*)d_in[3];
    const float* w1i = (const float*)d_in[4];
    const float* w2r = (const float*)d_in[5];
    const float* w2i = (const float*)d_in[6];
    float* out = (float*)d_out;

    // Workspace layout (42.0 MB total):
    //   [0, 33.5MB):   Xw (float2, pass1->2)  ALIASED with  Abh|Abl (pass4->5)
    //   [33.5, 37.7):  XhT   [37.7, 41.9): S   [41.9+): Wch|Wcl|Tgh|Tgl
    char* wsb = (char*)d_ws;
    ushort* Abh = (ushort*)wsb;                       // 16,777,216 B
    ushort* Abl = (ushort*)(wsb + 16777216);          // 16,777,216 B
    float2* Xw  = (float2*)wsb;                       // 33,554,432 B (aliases Abh/Abl)
    float2* XhT = (float2*)(wsb + 33554432);          //  4,194,304 B
    float2* S   = (float2*)(wsb + 37748736);          //  4,194,304 B
    ushort* Wch = (ushort*)(wsb + 41943040);          //      8,192 B
    ushort* Wcl = (ushort*)(wsb + 41951232);          //      8,192 B
    ushort* Tgh = (ushort*)(wsb + 41959424);          //     16,384 B
    ushort* Tgl = (ushort*)(wsb + 41975808);          //     16,384 B

    k_prep <<<  48, 256, 0, stream>>>(Wc, Wch, Wcl, Tgh, Tgl);
    k_dftw <<<8192, 128, 0, stream>>>(x, Xw);
    k_dfth <<<1024, 256, 0, stream>>>(Xw, XhT);
    k_modes<<< 512, 256, 0, stream>>>(XhT, w1r, w1i, w2r, w2i, S);
    k_invh <<<1024, 256, 0, stream>>>(S, Abh, Abl);   // Xw dead by now: alias safe
    k_final<<<4096, 256, 0, stream>>>(x, Wch, Wcl, Tgh, Tgl, Abh, Abl, bcv, out);
}

// Round 3
// 337.289 us; speedup vs baseline: 2.0944x; 1.1566x over previous
//
#include <hip/hip_runtime.h>
#include <hip/hip_bf16.h>
#include <math.h>

#define TWO_PI_256 0.024543692606170259678f  // 2*pi/256

typedef __attribute__((ext_vector_type(8))) short bf16x8;
typedef __attribute__((ext_vector_type(4))) float f32x4;

static __device__ __forceinline__ ushort bf16_rn(float a) {
    union { float f; unsigned int u; } v; v.f = a;
    unsigned int r = v.u + 0x7FFFu + ((v.u >> 16) & 1u);
    return (ushort)(r >> 16);
}
static __device__ __forceinline__ float bf16_to_f(ushort h) {
    union { unsigned int u; float f; } v; v.u = ((unsigned int)h) << 16;
    return v.f;
}
static __device__ __forceinline__ void split2(float a, ushort& hi, ushort& lo) {
    ushort h = bf16_rn(a);
    hi = h;
    lo = bf16_rn(a - bf16_to_f(h));
}

// hw cvt_pk path: 8 floats -> bf16-hi x8 + bf16-lo x8
static __device__ __forceinline__ void split8(const float* v, bf16x8& hi8, bf16x8& lo8) {
    union { ushort u[8]; bf16x8 v8; } H, L;
    #pragma unroll
    for (int j = 0; j < 8; j += 2) {
        __hip_bfloat162 hb = __float22bfloat162_rn(make_float2(v[j], v[j + 1]));
        ushort2 hu = *reinterpret_cast<ushort2*>(&hb);
        float fx = __uint_as_float((unsigned int)hu.x << 16);
        float fy = __uint_as_float((unsigned int)hu.y << 16);
        __hip_bfloat162 lb = __float22bfloat162_rn(make_float2(v[j] - fx, v[j + 1] - fy));
        ushort2 lu = *reinterpret_cast<ushort2*>(&lb);
        H.u[j] = hu.x; H.u[j + 1] = hu.y;
        L.u[j] = lu.x; L.u[j + 1] = lu.y;
    }
    hi8 = H.v8; lo8 = L.v8;
}

// branchless tanh-form GELU (max |delta| vs exact-erf gelu ~5e-4)
static __device__ __forceinline__ float gelu_f(float v) {
    float z = v * fmaf(v * v, 0.10294321f, 2.3022082f);   // 2u/ln2
    float e = __builtin_amdgcn_exp2f(z);
    return v - v * __builtin_amdgcn_rcpf(e + 1.0f);
}

// ---------------- Pass 0: bf16-split tables ----------------
// Wch/Wcl: [o][c].  Tgh/Tgl: [w][kz] (kz<16 cos, >=16 sin) for k_final.
// Tkh/Tkl: [j][w] (j<16 cos(2pi j w/256), j>=16 sin(2pi (j-16) w/256)) for k_dftw.
__global__ __launch_bounds__(256) void k_prep(const float* __restrict__ Wc,
        ushort* __restrict__ Wch, ushort* __restrict__ Wcl,
        ushort* __restrict__ Tgh, ushort* __restrict__ Tgl,
        ushort* __restrict__ Tkh, ushort* __restrict__ Tkl) {
    int g = blockIdx.x * 256 + threadIdx.x;
    if (g < 4096) {
        ushort h, l; split2(Wc[g], h, l);
        Wch[g] = h; Wcl[g] = l;
    }
    int t = g - 4096;
    if (t >= 0 && t < 8192) {
        int w = t >> 5, kz = t & 31, kx = kz & 15;
        int ph = (w * kx) & 255;
        float s, c; sincosf((float)ph * TWO_PI_256, &s, &c);
        float val = (kz < 16) ? c : s;
        ushort h, l; split2(val, h, l);
        Tgh[t] = h; Tgl[t] = l;
    }
    int t2 = g - 12288;
    if (t2 >= 0 && t2 < 8192) {
        int j = t2 >> 8, w = t2 & 255, kx = j & 15;
        int ph = (w * kx) & 255;
        float s, c; sincosf((float)ph * TWO_PI_256, &s, &c);
        float val = (j < 16) ? c : s;
        ushort h, l; split2(val, h, l);
        Tkh[t2] = h; Tkl[t2] = l;
    }
}

// ---------------- Pass 1: partial DFT over w via MFMA ----------------
// Block: (plane bc, 32-row h-chunk). C[32h x 32j] = x[32h x 256w] * Tk^T.
// Xw[bc][kx][h] = (D[h][kx], -D[h][16+kx])
__global__ __launch_bounds__(128) void k_dftw(const float* __restrict__ x,
        const ushort* __restrict__ Tkh, const ushort* __restrict__ Tkl,
        float2* __restrict__ Xw) {
    const int tid = threadIdx.x;
    const int lane = tid & 63;
    const int wv = tid >> 6;
    const int bc = blockIdx.x >> 3;
    const int h0 = (blockIdx.x & 7) << 5;
    __shared__ ushort Ah[32][256];   // [h][w] bf16-hi, octet^(h&7) swizzled
    __shared__ ushort Al[32][256];

    // stage + split x[bc][h0..h0+32)[0..256)
    const float* xp = x + ((size_t)bc << 16) + ((size_t)h0 << 8);
    #pragma unroll
    for (int i = 0; i < 8; ++i) {
        int f8 = tid + (i << 7);         // 0..1023 octets
        int hh = f8 >> 5, oct = f8 & 31;
        float v[8];
        *(float4*)&v[0] = *(const float4*)(xp + (hh << 8) + (oct << 3));
        *(float4*)&v[4] = *(const float4*)(xp + (hh << 8) + (oct << 3) + 4);
        bf16x8 hi8, lo8;
        split8(v, hi8, lo8);
        int bidx = oct ^ (hh & 7);
        *(bf16x8*)(&Ah[0][0] + (hh << 8) + (bidx << 3)) = hi8;
        *(bf16x8*)(&Al[0][0] + (hh << 8) + (bidx << 3)) = lo8;
    }
    __syncthreads();

    const int l15 = lane & 15, l4 = lane >> 4;
    const int row = (wv << 4) + l15;
    const int rbase = row << 8;
    const int rs = row & 7;

    f32x4 acc0 = {0.f, 0.f, 0.f, 0.f}, acc1 = {0.f, 0.f, 0.f, 0.f};
    #pragma unroll 4
    for (int ks = 0; ks < 8; ++ks) {
        int boff = ((((ks << 2) + l4) ^ rs) << 3);
        bf16x8 a_h = *(const bf16x8*)(&Ah[0][0] + rbase + boff);
        bf16x8 a_l = *(const bf16x8*)(&Al[0][0] + rbase + boff);
        int toff = (l15 << 8) + (ks << 5) + (l4 << 3);
        bf16x8 b0h = *(const bf16x8*)(Tkh + toff);
        bf16x8 b0l = *(const bf16x8*)(Tkl + toff);
        bf16x8 b1h = *(const bf16x8*)(Tkh + 4096 + toff);
        bf16x8 b1l = *(const bf16x8*)(Tkl + 4096 + toff);
        acc0 = __builtin_amdgcn_mfma_f32_16x16x32_bf16(a_h, b0h, acc0, 0, 0, 0);
        acc0 = __builtin_amdgcn_mfma_f32_16x16x32_bf16(a_h, b0l, acc0, 0, 0, 0);
        acc0 = __builtin_amdgcn_mfma_f32_16x16x32_bf16(a_l, b0h, acc0, 0, 0, 0);
        acc1 = __builtin_amdgcn_mfma_f32_16x16x32_bf16(a_h, b1h, acc1, 0, 0, 0);
        acc1 = __builtin_amdgcn_mfma_f32_16x16x32_bf16(a_h, b1l, acc1, 0, 0, 0);
        acc1 = __builtin_amdgcn_mfma_f32_16x16x32_bf16(a_l, b1h, acc1, 0, 0, 0);
    }
    // D: col=l15 -> j (=kx), row=l4*4+r -> h (within wave's 16)
    float2* op = Xw + ((size_t)bc << 12) + (l15 << 8) + h0 + (wv << 4) + (l4 << 2);
    float4 s0 = make_float4(acc0[0], -acc1[0], acc0[1], -acc1[1]);
    float4 s1 = make_float4(acc0[2], -acc1[2], acc0[3], -acc1[3]);
    *(float4*)(op) = s0;
    *(float4*)(op + 2) = s1;
}

// ---------------- Pass 2: DFT over h at 32 ky values ----------------
__global__ __launch_bounds__(256) void k_dfth(const float2* __restrict__ Xw,
                                              float2* __restrict__ XhT) {
    const int tid = threadIdx.x;
    const int bc = blockIdx.x;
    __shared__ float2 xw[16][258];
    __shared__ float2 tw[256];
    {
        float s, c;
        sincosf((float)tid * TWO_PI_256, &s, &c);
        tw[tid] = make_float2(c, s);
    }
    const float2* src = Xw + ((size_t)bc << 12);
    #pragma unroll
    for (int k = 0; k < 16; ++k) {
        int f = tid + (k << 8);
        xw[f >> 8][f & 255] = src[f];
    }
    __syncthreads();
    const int kx = tid & 15, slot = tid >> 4;
    const int physb = 240 + slot;
    float tr = 0.f, ti = 0.f, br = 0.f, bi = 0.f;
    int t1 = 0, t2 = 0;
    for (int h = 0; h < 256; ++h) {
        float2 v = xw[kx][h];
        float2 cA = tw[t1];
        float2 cB = tw[t2];
        tr = fmaf(v.x, cA.x, fmaf(v.y, cA.y, tr));
        ti = fmaf(v.y, cA.x, fmaf(-v.x, cA.y, ti));
        br = fmaf(v.x, cB.x, fmaf(v.y, cB.y, br));
        bi = fmaf(v.y, cB.x, fmaf(-v.x, cB.y, bi));
        t1 = (t1 + slot) & 255;
        t2 = (t2 + physb) & 255;
    }
    XhT[(size_t)(((slot << 4) + kx) << 10) + bc] = make_float2(tr, ti);
    XhT[(size_t)((((16 + slot) << 4) + kx) << 10) + bc] = make_float2(br, bi);
}

// ---------------- Pass 3: per-mode 64x64 complex channel mix ----------------
__global__ __launch_bounds__(256) void k_modes(const float2* __restrict__ XhT,
        const float* __restrict__ w1r, const float* __restrict__ w1i,
        const float* __restrict__ w2r, const float* __restrict__ w2i,
        float2* __restrict__ S) {
    const int tid = threadIdx.x;
    const int mode = blockIdx.x;
    const int kyIdx = mode >> 4, kx = mode & 15;
    const int xy = ((kyIdx & 15) << 4) + kx;
    const float* __restrict__ wr = (kyIdx < 16) ? w1r : w2r;
    const float* __restrict__ wi = (kyIdx < 16) ? w1i : w2i;
    __shared__ float2 xin[16][65];
    __shared__ float2 wlds[64][64];
    const float2* xsrc = XhT + ((size_t)mode << 10);
    #pragma unroll
    for (int k = 0; k < 4; ++k) {
        int f = tid + (k << 8);
        xin[f >> 6][f & 63] = xsrc[f];
    }
    const float sc = 1.52587890625e-05f;
    #pragma unroll
    for (int k = 0; k < 16; ++k) {
        int e = tid + (k << 8);
        size_t a = ((size_t)e << 8) + xy;
        wlds[e >> 6][e & 63] = make_float2(wr[a] * sc, wi[a] * sc);
    }
    __syncthreads();
    const int b = tid >> 4, o0 = tid & 15;
    float2 acc[4] = {};
    for (int i = 0; i < 64; ++i) {
        float2 a = xin[b][i];
        #pragma unroll
        for (int k = 0; k < 4; ++k) {
            float2 wv = wlds[i][o0 + (k << 4)];
            acc[k].x = fmaf(a.x, wv.x, fmaf(-a.y, wv.y, acc[k].x));
            acc[k].y = fmaf(a.x, wv.y, fmaf(a.y, wv.x, acc[k].y));
        }
    }
    float2* sp = S + ((size_t)((b << 6) + o0) << 9) + mode;
    #pragma unroll
    for (int k = 0; k < 4; ++k) sp[(size_t)(k << 13)] = acc[k];
}

// ---------------- Pass 4: inverse DFT over h -> bf16-split Z-columns ----------------
__global__ __launch_bounds__(256) void k_invh(const float2* __restrict__ S,
                                              ushort* __restrict__ Ah,
                                              ushort* __restrict__ Al) {
    const int tid = threadIdx.x;
    const int bo = blockIdx.x;
    const int b = bo >> 6, o = bo & 63;
    __shared__ float2 sl[32][16];
    __shared__ float2 tw[256];
    {
        float s, c;
        sincosf((float)tid * TWO_PI_256, &s, &c);
        tw[tid] = make_float2(c, s);
    }
    ((float2*)sl)[tid] = S[((size_t)bo << 9) + tid];
    ((float2*)sl)[tid + 256] = S[((size_t)bo << 9) + tid + 256];
    __syncthreads();
    const int kx = tid & 15, hs = tid >> 4;
    float2 sr[32];
    #pragma unroll
    for (int ky = 0; ky < 32; ++ky) sr[ky] = sl[ky][kx];
    const float scl = kx ? 2.0f : 1.0f;
    for (int j = 0; j < 16; ++j) {
        const int h = (hs << 4) + j;
        float ar = 0.f, ai = 0.f;
        #pragma unroll
        for (int ky = 0; ky < 32; ++ky) {
            const int phys = (ky < 16) ? ky : (224 + ky);
            const int t = (phys * h) & 255;
            float2 s = sr[ky];
            float2 cs = tw[t];
            ar = fmaf(s.x, cs.x, fmaf(-s.y, cs.y, ar));
            ai = fmaf(s.y, cs.x, fmaf(s.x, cs.y, ai));
        }
        size_t base = (((size_t)((b << 8) + h) << 6) + o) << 5;
        ushort hh, ll;
        split2(ar * scl, hh, ll);
        Ah[base + kx] = hh;      Al[base + kx] = ll;
        split2(-ai * scl, hh, ll);
        Ah[base + 16 + kx] = hh; Al[base + 16 + kx] = ll;
    }
}

// ---------------- Pass 5: MFMA conv + inv-DFT-w + bias + GELU ----------------
__global__ __launch_bounds__(256, 3) void k_final(const float* __restrict__ x,
        const ushort* __restrict__ Wch, const ushort* __restrict__ Wcl,
        const ushort* __restrict__ Tgh, const ushort* __restrict__ Tgl,
        const ushort* __restrict__ Abh, const ushort* __restrict__ Abl,
        const float* __restrict__ bcv, float* __restrict__ out) {
    const int tid = threadIdx.x;
    const int lane = tid & 63;
    const int wv = tid >> 6;
    const int blk = blockIdx.x;
    const int wq = blk & 3, ht = (blk >> 2) & 63, b = blk >> 8;
    const int w0 = wq << 6;

    __shared__ ushort Xh[64][128];
    __shared__ ushort Xl[64][128];

    const int l15 = lane & 15, l4 = lane >> 4;
    const int mt0 = (wv >> 1) << 1;
    const int nt0 = (wv & 1) << 1;
    const int wloc = tid & 63, cb0 = tid >> 6;

    const float* xb = x + ((size_t)b << 22) + ((size_t)(ht << 2) << 8) + w0 + wloc;

    float g[2][2][8];
    // prologue: issue x loads for hh=0 ASAP
    #pragma unroll
    for (int i = 0; i < 2; ++i) {
        const float* xpc = xb + ((size_t)(cb0 + (i << 2)) << 19);
        #pragma unroll
        for (int j = 0; j < 8; ++j) g[0][i][j] = xpc[(size_t)j << 16];
    }

    // T staging (h-invariant, octets 8..15 under swizzle)
    {
        size_t gg = ((size_t)(w0 + wloc) << 5) + (cb0 << 3);
        bf16x8 th = *(const bf16x8*)(Tgh + gg);
        bf16x8 tl = *(const bf16x8*)(Tgl + gg);
        int bidx = (8 + cb0) ^ (wloc & 7);
        *(bf16x8*)(&Xh[0][0] + (wloc << 7) + (bidx << 3)) = th;
        *(bf16x8*)(&Xl[0][0] + (wloc << 7) + (bidx << 3)) = tl;
    }

    // Wc A-frags + bias (block-invariant)
    bf16x8 aW[2][2][2];
    #pragma unroll
    for (int mi = 0; mi < 2; ++mi) {
        int o = ((mt0 + mi) << 4) + l15;
        #pragma unroll
        for (int ks = 0; ks < 2; ++ks) {
            size_t gg = ((size_t)o << 6) + (ks << 5) + (l4 << 3);
            aW[mi][ks][0] = *(const bf16x8*)(Wch + gg);
            aW[mi][ks][1] = *(const bf16x8*)(Wcl + gg);
        }
    }
    float bias[2][4];
    #pragma unroll
    for (int mi = 0; mi < 2; ++mi)
        #pragma unroll
        for (int r = 0; r < 4; ++r)
            bias[mi][r] = bcv[((mt0 + mi) << 4) + (l4 << 2) + r];

    #pragma unroll
    for (int hh = 0; hh < 4; ++hh) {
        const int h = (ht << 2) + hh;
        const int cur = hh & 1, nxt = cur ^ 1;

        // Z A-frags for this h (L2-resident; latency hidden by barriers+ds_write)
        bf16x8 zH[2], zL[2];
        #pragma unroll
        for (int mi = 0; mi < 2; ++mi) {
            int o = ((mt0 + mi) << 4) + l15;
            size_t gg = ((((size_t)((b << 8) + h) << 6) + o) << 5) + (l4 << 3);
            zH[mi] = *(const bf16x8*)(Abh + gg);
            zL[mi] = *(const bf16x8*)(Abl + gg);
        }

        // convert staged x (loaded during previous iteration's MFMA)
        bf16x8 hb[2], lb[2];
        split8(g[cur][0], hb[0], lb[0]);
        split8(g[cur][1], hb[1], lb[1]);

        __syncthreads();             // prior tile's B reads complete
        #pragma unroll
        for (int i = 0; i < 2; ++i) {
            int bidx = (cb0 + (i << 2)) ^ (wloc & 7);
            *(bf16x8*)(&Xh[0][0] + (wloc << 7) + (bidx << 3)) = hb[i];
            *(bf16x8*)(&Xl[0][0] + (wloc << 7) + (bidx << 3)) = lb[i];
        }
        __syncthreads();

        // prefetch next h's x into the other buffer (in flight during MFMA+epilogue)
        if (hh < 3) {
            #pragma unroll
            for (int i = 0; i < 2; ++i) {
                const float* xpc = xb + ((size_t)(cb0 + (i << 2)) << 19) + ((hh + 1) << 8);
                #pragma unroll
                for (int j = 0; j < 8; ++j) g[nxt][i][j] = xpc[(size_t)j << 16];
            }
        }

        // MFMA: 3 k-steps x 3 split-products x (2m x 2n)
        f32x4 acc[2][2];
        #pragma unroll
        for (int mi = 0; mi < 2; ++mi)
            #pragma unroll
            for (int ni = 0; ni < 2; ++ni)
                acc[mi][ni] = (f32x4){0.f, 0.f, 0.f, 0.f};

        #pragma unroll
        for (int ks = 0; ks < 3; ++ks) {
            bf16x8 bh[2], bl[2];
            #pragma unroll
            for (int ni = 0; ni < 2; ++ni) {
                int w = ((nt0 + ni) << 4) + l15;
                int bidx = ((ks << 2) + l4) ^ (w & 7);
                bh[ni] = *(const bf16x8*)(&Xh[0][0] + (w << 7) + (bidx << 3));
                bl[ni] = *(const bf16x8*)(&Xl[0][0] + (w << 7) + (bidx << 3));
            }
            #pragma unroll
            for (int mi = 0; mi < 2; ++mi) {
                bf16x8 ah_ = (ks < 2) ? aW[mi][ks][0] : zH[mi];
                bf16x8 al_ = (ks < 2) ? aW[mi][ks][1] : zL[mi];
                #pragma unroll
                for (int ni = 0; ni < 2; ++ni) {
                    acc[mi][ni] = __builtin_amdgcn_mfma_f32_16x16x32_bf16(ah_, bh[ni], acc[mi][ni], 0, 0, 0);
                    acc[mi][ni] = __builtin_amdgcn_mfma_f32_16x16x32_bf16(ah_, bl[ni], acc[mi][ni], 0, 0, 0);
                    acc[mi][ni] = __builtin_amdgcn_mfma_f32_16x16x32_bf16(al_, bh[ni], acc[mi][ni], 0, 0, 0);
                }
            }
        }

        // epilogue: bias + GELU + store
        #pragma unroll
        for (int mi = 0; mi < 2; ++mi) {
            #pragma unroll
            for (int ni = 0; ni < 2; ++ni) {
                int wg = w0 + ((nt0 + ni) << 4) + l15;
                #pragma unroll
                for (int r = 0; r < 4; ++r) {
                    int o = ((mt0 + mi) << 4) + (l4 << 2) + r;
                    float v = acc[mi][ni][r] + bias[mi][r];
                    out[((size_t)((b << 6) + o) << 16) + ((size_t)h << 8) + wg] = gelu_f(v);
                }
            }
        }
    }
}

extern "C" void kernel_launch(void* const* d_in, const int* in_sizes, int n_in,
                              void* d_out, int out_size, void* d_ws, size_t ws_size,
                              hipStream_t stream) {
    const float* x   = (const float*)d_in[0];
    const float* Wc  = (const float*)d_in[1];
    const float* bcv = (const float*)d_in[2];
    const float* w1r = (const float*)d_in[3];
    const float* w1i = (const float*)d_in[4];
    const float* w2r = (const float*)d_in[5];
    const float* w2i = (const float*)d_in[6];
    float* out = (float*)d_out;

    // Workspace layout (42.0 MB):
    //   [0, 33.5MB):   Xw (pass1->2)  ALIASED with  Abh|Abl (pass4->5)
    //   [33.5, 37.7):  XhT
    //   [37.7, 41.9):  S  — head ALIASED with Tkh|Tkl (prep->dftw; dead before k_modes writes S)
    //   [41.9+):       Wch|Wcl|Tgh|Tgl
    char* wsb = (char*)d_ws;
    ushort* Abh = (ushort*)wsb;
    ushort* Abl = (ushort*)(wsb + 16777216);
    float2* Xw  = (float2*)wsb;
    float2* XhT = (float2*)(wsb + 33554432);
    float2* S   = (float2*)(wsb + 37748736);
    ushort* Tkh = (ushort*)(wsb + 37748736);          // aliases S head; Tk dead before k_modes
    ushort* Tkl = (ushort*)(wsb + 37748736 + 16384);
    ushort* Wch = (ushort*)(wsb + 41943040);
    ushort* Wcl = (ushort*)(wsb + 41951232);
    ushort* Tgh = (ushort*)(wsb + 41959424);
    ushort* Tgl = (ushort*)(wsb + 41975808);

    k_prep <<<  80, 256, 0, stream>>>(Wc, Wch, Wcl, Tgh, Tgl, Tkh, Tkl);
    k_dftw <<<8192, 128, 0, stream>>>(x, Tkh, Tkl, Xw);
    k_dfth <<<1024, 256, 0, stream>>>(Xw, XhT);
    k_modes<<< 512, 256, 0, stream>>>(XhT, w1r, w1i, w2r, w2i, S);
    k_invh <<<1024, 256, 0, stream>>>(S, Abh, Abl);
    k_final<<<4096, 256, 0, stream>>>(x, Wch, Wcl, Tgh, Tgl, Abh, Abl, bcv, out);
}

// Round 4
// 313.461 us; speedup vs baseline: 2.2536x; 1.0760x over previous
//
#include <hip/hip_runtime.h>
#include <hip/hip_bf16.h>
#include <math.h>

#define TWO_PI_256 0.024543692606170259678f  // 2*pi/256

typedef __attribute__((ext_vector_type(8))) short bf16x8;
typedef __attribute__((ext_vector_type(4))) float f32x4;

static __device__ __forceinline__ ushort bf16_rn(float a) {
    union { float f; unsigned int u; } v; v.f = a;
    unsigned int r = v.u + 0x7FFFu + ((v.u >> 16) & 1u);
    return (ushort)(r >> 16);
}
static __device__ __forceinline__ float bf16_to_f(ushort h) {
    union { unsigned int u; float f; } v; v.u = ((unsigned int)h) << 16;
    return v.f;
}
static __device__ __forceinline__ void split2(float a, ushort& hi, ushort& lo) {
    ushort h = bf16_rn(a);
    hi = h;
    lo = bf16_rn(a - bf16_to_f(h));
}

// hw cvt_pk path: 8 floats -> bf16-hi x8 + bf16-lo x8
static __device__ __forceinline__ void split8(const float* v, bf16x8& hi8, bf16x8& lo8) {
    union { ushort u[8]; bf16x8 v8; } H, L;
    #pragma unroll
    for (int j = 0; j < 8; j += 2) {
        __hip_bfloat162 hb = __float22bfloat162_rn(make_float2(v[j], v[j + 1]));
        ushort2 hu = *reinterpret_cast<ushort2*>(&hb);
        float fx = __uint_as_float((unsigned int)hu.x << 16);
        float fy = __uint_as_float((unsigned int)hu.y << 16);
        __hip_bfloat162 lb = __float22bfloat162_rn(make_float2(v[j] - fx, v[j + 1] - fy));
        ushort2 lu = *reinterpret_cast<ushort2*>(&lb);
        H.u[j] = hu.x; H.u[j + 1] = hu.y;
        L.u[j] = lu.x; L.u[j + 1] = lu.y;
    }
    hi8 = H.v8; lo8 = L.v8;
}

// branchless tanh-form GELU (max |delta| vs exact-erf gelu ~5e-4)
static __device__ __forceinline__ float gelu_f(float v) {
    float z = v * fmaf(v * v, 0.10294321f, 2.3022082f);   // 2u/ln2
    float e = __builtin_amdgcn_exp2f(z);
    return v - v * __builtin_amdgcn_rcpf(e + 1.0f);
}

// ---------------- Pass 0: bf16-split tables ----------------
__global__ __launch_bounds__(256) void k_prep(const float* __restrict__ Wc,
        ushort* __restrict__ Wch, ushort* __restrict__ Wcl,
        ushort* __restrict__ Tgh, ushort* __restrict__ Tgl,
        ushort* __restrict__ Tkh, ushort* __restrict__ Tkl) {
    int g = blockIdx.x * 256 + threadIdx.x;
    if (g < 4096) {
        ushort h, l; split2(Wc[g], h, l);
        Wch[g] = h; Wcl[g] = l;
    }
    int t = g - 4096;
    if (t >= 0 && t < 8192) {
        int w = t >> 5, kz = t & 31, kx = kz & 15;
        int ph = (w * kx) & 255;
        float s, c; sincosf((float)ph * TWO_PI_256, &s, &c);
        float val = (kz < 16) ? c : s;
        ushort h, l; split2(val, h, l);
        Tgh[t] = h; Tgl[t] = l;
    }
    int t2 = g - 12288;
    if (t2 >= 0 && t2 < 8192) {
        int j = t2 >> 8, w = t2 & 255, kx = j & 15;
        int ph = (w * kx) & 255;
        float s, c; sincosf((float)ph * TWO_PI_256, &s, &c);
        float val = (j < 16) ? c : s;
        ushort h, l; split2(val, h, l);
        Tkh[t2] = h; Tkl[t2] = l;
    }
}

// ---------------- Pass 1: partial DFT over w via MFMA ----------------
__global__ __launch_bounds__(128) void k_dftw(const float* __restrict__ x,
        const ushort* __restrict__ Tkh, const ushort* __restrict__ Tkl,
        float2* __restrict__ Xw) {
    const int tid = threadIdx.x;
    const int lane = tid & 63;
    const int wv = tid >> 6;
    const int bc = blockIdx.x >> 3;
    const int h0 = (blockIdx.x & 7) << 5;
    __shared__ ushort Ah[32][256];   // [h][w] bf16-hi, octet^(h&7) swizzled
    __shared__ ushort Al[32][256];

    const float* xp = x + ((size_t)bc << 16) + ((size_t)h0 << 8);
    #pragma unroll
    for (int i = 0; i < 8; ++i) {
        int f8 = tid + (i << 7);
        int hh = f8 >> 5, oct = f8 & 31;
        float v[8];
        *(float4*)&v[0] = *(const float4*)(xp + (hh << 8) + (oct << 3));
        *(float4*)&v[4] = *(const float4*)(xp + (hh << 8) + (oct << 3) + 4);
        bf16x8 hi8, lo8;
        split8(v, hi8, lo8);
        int bidx = oct ^ (hh & 7);
        *(bf16x8*)(&Ah[0][0] + (hh << 8) + (bidx << 3)) = hi8;
        *(bf16x8*)(&Al[0][0] + (hh << 8) + (bidx << 3)) = lo8;
    }
    __syncthreads();

    const int l15 = lane & 15, l4 = lane >> 4;
    const int row = (wv << 4) + l15;
    const int rbase = row << 8;
    const int rs = row & 7;

    f32x4 acc0 = {0.f, 0.f, 0.f, 0.f}, acc1 = {0.f, 0.f, 0.f, 0.f};
    #pragma unroll 4
    for (int ks = 0; ks < 8; ++ks) {
        int boff = ((((ks << 2) + l4) ^ rs) << 3);
        bf16x8 a_h = *(const bf16x8*)(&Ah[0][0] + rbase + boff);
        bf16x8 a_l = *(const bf16x8*)(&Al[0][0] + rbase + boff);
        int toff = (l15 << 8) + (ks << 5) + (l4 << 3);
        bf16x8 b0h = *(const bf16x8*)(Tkh + toff);
        bf16x8 b0l = *(const bf16x8*)(Tkl + toff);
        bf16x8 b1h = *(const bf16x8*)(Tkh + 4096 + toff);
        bf16x8 b1l = *(const bf16x8*)(Tkl + 4096 + toff);
        acc0 = __builtin_amdgcn_mfma_f32_16x16x32_bf16(a_h, b0h, acc0, 0, 0, 0);
        acc0 = __builtin_amdgcn_mfma_f32_16x16x32_bf16(a_h, b0l, acc0, 0, 0, 0);
        acc0 = __builtin_amdgcn_mfma_f32_16x16x32_bf16(a_l, b0h, acc0, 0, 0, 0);
        acc1 = __builtin_amdgcn_mfma_f32_16x16x32_bf16(a_h, b1h, acc1, 0, 0, 0);
        acc1 = __builtin_amdgcn_mfma_f32_16x16x32_bf16(a_h, b1l, acc1, 0, 0, 0);
        acc1 = __builtin_amdgcn_mfma_f32_16x16x32_bf16(a_l, b1h, acc1, 0, 0, 0);
    }
    float2* op = Xw + ((size_t)bc << 12) + (l15 << 8) + h0 + (wv << 4) + (l4 << 2);
    float4 s0 = make_float4(acc0[0], -acc1[0], acc0[1], -acc1[1]);
    float4 s1 = make_float4(acc0[2], -acc1[2], acc0[3], -acc1[3]);
    *(float4*)(op) = s0;
    *(float4*)(op + 2) = s1;
}

// ---------------- Pass 2: DFT over h at 32 ky values ----------------
__global__ __launch_bounds__(256) void k_dfth(const float2* __restrict__ Xw,
                                              float2* __restrict__ XhT) {
    const int tid = threadIdx.x;
    const int bc = blockIdx.x;
    __shared__ float2 xw[16][258];
    __shared__ float2 tw[256];
    {
        float s, c;
        sincosf((float)tid * TWO_PI_256, &s, &c);
        tw[tid] = make_float2(c, s);
    }
    const float2* src = Xw + ((size_t)bc << 12);
    #pragma unroll
    for (int k = 0; k < 16; ++k) {
        int f = tid + (k << 8);
        xw[f >> 8][f & 255] = src[f];
    }
    __syncthreads();
    const int kx = tid & 15, slot = tid >> 4;
    const int physb = 240 + slot;
    float tr = 0.f, ti = 0.f, br = 0.f, bi = 0.f;
    int t1 = 0, t2 = 0;
    for (int h = 0; h < 256; ++h) {
        float2 v = xw[kx][h];
        float2 cA = tw[t1];
        float2 cB = tw[t2];
        tr = fmaf(v.x, cA.x, fmaf(v.y, cA.y, tr));
        ti = fmaf(v.y, cA.x, fmaf(-v.x, cA.y, ti));
        br = fmaf(v.x, cB.x, fmaf(v.y, cB.y, br));
        bi = fmaf(v.y, cB.x, fmaf(-v.x, cB.y, bi));
        t1 = (t1 + slot) & 255;
        t2 = (t2 + physb) & 255;
    }
    XhT[(size_t)(((slot << 4) + kx) << 10) + bc] = make_float2(tr, ti);
    XhT[(size_t)((((16 + slot) << 4) + kx) << 10) + bc] = make_float2(br, bi);
}

// ---------------- Pass 3: channel mix, coalesced-weight version ----------------
// Block = (kyIdx 0..31, o-chunk 0..7). Each 64B weight line (16 kx at fixed i,o)
// is consumed entirely by one block -> zero gather inflation.
__global__ __launch_bounds__(256) void k_modes(const float2* __restrict__ XhT,
        const float* __restrict__ w1r, const float* __restrict__ w1i,
        const float* __restrict__ w2r, const float* __restrict__ w2i,
        float2* __restrict__ S) {
    const int tid = threadIdx.x;
    const int kyIdx = blockIdx.x >> 3;
    const int oc    = blockIdx.x & 7;
    const int xy0   = (kyIdx & 15) << 4;
    const float* __restrict__ wr = (kyIdx < 16) ? w1r : w2r;
    const float* __restrict__ wi = (kyIdx < 16) ? w1i : w2i;

    __shared__ float2 Xl[16][16][17];     // [kx][ii][b] (+pad)
    __shared__ float  Wr_l[16][8][20];    // [ii][oj][kx] (+pad)
    __shared__ float  Wi_l[16][8][20];

    // compute-role indices
    const int b  = tid >> 4;
    const int o8 = (tid >> 1) & 7;
    const int kh = tid & 1;

    // staging-role indices
    const int s_ii = tid >> 4, s_oj = (tid >> 1) & 7, s_part = tid & 1;  // W rows
    const int s_kx = tid >> 4, s_bb = tid & 15;                          // X rows

    float2 acc[8];
    #pragma unroll
    for (int j = 0; j < 8; ++j) acc[j] = make_float2(0.f, 0.f);

    for (int ic = 0; ic < 4; ++ic) {
        if (ic) __syncthreads();
        // stage W chunk: [16 ii][8 oj][16 kx] for r and i parts
        {
            const float* src = s_part ? wi : wr;
            size_t off = ((size_t)(((ic << 4) + s_ii) * 64 + (oc << 3) + s_oj) << 8) + xy0;
            float4 v0 = *(const float4*)(src + off);
            float4 v1 = *(const float4*)(src + off + 4);
            float4 v2 = *(const float4*)(src + off + 8);
            float4 v3 = *(const float4*)(src + off + 12);
            float* dst = s_part ? &Wi_l[s_ii][s_oj][0] : &Wr_l[s_ii][s_oj][0];
            *(float4*)(dst)      = v0;
            *(float4*)(dst + 4)  = v1;
            *(float4*)(dst + 8)  = v2;
            *(float4*)(dst + 12) = v3;
        }
        // stage X chunk: [16 kx][16 ii][16 b]
        {
            const float2* src = XhT + (((size_t)((kyIdx << 4) + s_kx)) << 10)
                                    + (s_bb << 6) + (ic << 4);
            float2 xv[16];
            #pragma unroll
            for (int q = 0; q < 8; ++q)
                *(float4*)&xv[q << 1] = *(const float4*)(src + (q << 1));
            #pragma unroll
            for (int ii = 0; ii < 16; ++ii)
                Xl[s_kx][ii][s_bb] = xv[ii];
        }
        __syncthreads();

        #pragma unroll 4
        for (int ii = 0; ii < 16; ++ii) {
            float4 wr0 = *(const float4*)&Wr_l[ii][o8][kh << 3];
            float4 wr1 = *(const float4*)&Wr_l[ii][o8][(kh << 3) + 4];
            float4 wi0 = *(const float4*)&Wi_l[ii][o8][kh << 3];
            float4 wi1 = *(const float4*)&Wi_l[ii][o8][(kh << 3) + 4];
            const float wrv[8] = {wr0.x, wr0.y, wr0.z, wr0.w, wr1.x, wr1.y, wr1.z, wr1.w};
            const float wiv[8] = {wi0.x, wi0.y, wi0.z, wi0.w, wi1.x, wi1.y, wi1.z, wi1.w};
            #pragma unroll
            for (int j = 0; j < 8; ++j) {
                float2 xv = Xl[(kh << 3) + j][ii][b];
                acc[j].x = fmaf(xv.x, wrv[j], fmaf(-xv.y, wiv[j], acc[j].x));
                acc[j].y = fmaf(xv.x, wiv[j], fmaf( xv.y, wrv[j], acc[j].y));
            }
        }
    }

    const float sc = 1.52587890625e-05f;   // 1/65536
    const int o = (oc << 3) + o8;
    float2* sp = S + (((size_t)(b << 6) + o) << 9) + (kyIdx << 4) + (kh << 3);
    #pragma unroll
    for (int q = 0; q < 4; ++q) {
        float4 v = make_float4(acc[2 * q].x * sc, acc[2 * q].y * sc,
                               acc[2 * q + 1].x * sc, acc[2 * q + 1].y * sc);
        *(float4*)(sp + (q << 1)) = v;
    }
}

// ---------------- Pass 4: inverse DFT over h -> bf16-split Z-columns ----------------
__global__ __launch_bounds__(256) void k_invh(const float2* __restrict__ S,
                                              ushort* __restrict__ Ah,
                                              ushort* __restrict__ Al) {
    const int tid = threadIdx.x;
    const int bo = blockIdx.x;
    const int b = bo >> 6, o = bo & 63;
    __shared__ float2 sl[32][16];
    __shared__ float2 tw[256];
    {
        float s, c;
        sincosf((float)tid * TWO_PI_256, &s, &c);
        tw[tid] = make_float2(c, s);
    }
    ((float2*)sl)[tid] = S[((size_t)bo << 9) + tid];
    ((float2*)sl)[tid + 256] = S[((size_t)bo << 9) + tid + 256];
    __syncthreads();
    const int kx = tid & 15, hs = tid >> 4;
    float2 sr[32];
    #pragma unroll
    for (int ky = 0; ky < 32; ++ky) sr[ky] = sl[ky][kx];
    const float scl = kx ? 2.0f : 1.0f;
    for (int j = 0; j < 16; ++j) {
        const int h = (hs << 4) + j;
        float ar = 0.f, ai = 0.f;
        #pragma unroll
        for (int ky = 0; ky < 32; ++ky) {
            const int phys = (ky < 16) ? ky : (224 + ky);
            const int t = (phys * h) & 255;
            float2 s = sr[ky];
            float2 cs = tw[t];
            ar = fmaf(s.x, cs.x, fmaf(-s.y, cs.y, ar));
            ai = fmaf(s.y, cs.x, fmaf(s.x, cs.y, ai));
        }
        size_t base = (((size_t)((b << 8) + h) << 6) + o) << 5;
        ushort hh, ll;
        split2(ar * scl, hh, ll);
        Ah[base + kx] = hh;      Al[base + kx] = ll;
        split2(-ai * scl, hh, ll);
        Ah[base + 16 + kx] = hh; Al[base + 16 + kx] = ll;
    }
}

// ---------------- Pass 5: MFMA conv + inv-DFT-w + bias + GELU ----------------
// T1 XCD swizzle: the 4 wq-siblings of each (b,ht) land on the SAME XCD so the
// shared Z block (32 KB) is an L2 hit instead of 4x HBM fetches.
__global__ __launch_bounds__(256, 3) void k_final(const float* __restrict__ x,
        const ushort* __restrict__ Wch, const ushort* __restrict__ Wcl,
        const ushort* __restrict__ Tgh, const ushort* __restrict__ Tgl,
        const ushort* __restrict__ Abh, const ushort* __restrict__ Abl,
        const float* __restrict__ bcv, float* __restrict__ out) {
    const int tid = threadIdx.x;
    const int lane = tid & 63;
    const int wv = tid >> 6;
    const int bid = blockIdx.x;
    const int gid = ((bid >> 5) << 3) | (bid & 7);   // 0..1023 = (b, ht)
    const int wq  = (bid >> 3) & 3;                  // siblings: same (bid & 7) -> same XCD
    const int b = gid >> 6, ht = gid & 63;
    const int w0 = wq << 6;

    __shared__ ushort Xh[64][128];
    __shared__ ushort Xl[64][128];

    const int l15 = lane & 15, l4 = lane >> 4;
    const int mt0 = (wv >> 1) << 1;
    const int nt0 = (wv & 1) << 1;
    const int wloc = tid & 63, cb0 = tid >> 6;

    const float* xb = x + ((size_t)b << 22) + ((size_t)(ht << 2) << 8) + w0 + wloc;

    float g[2][2][8];
    #pragma unroll
    for (int i = 0; i < 2; ++i) {
        const float* xpc = xb + ((size_t)(cb0 + (i << 2)) << 19);
        #pragma unroll
        for (int j = 0; j < 8; ++j) g[0][i][j] = xpc[(size_t)j << 16];
    }

    {
        size_t gg = ((size_t)(w0 + wloc) << 5) + (cb0 << 3);
        bf16x8 th = *(const bf16x8*)(Tgh + gg);
        bf16x8 tl = *(const bf16x8*)(Tgl + gg);
        int bidx = (8 + cb0) ^ (wloc & 7);
        *(bf16x8*)(&Xh[0][0] + (wloc << 7) + (bidx << 3)) = th;
        *(bf16x8*)(&Xl[0][0] + (wloc << 7) + (bidx << 3)) = tl;
    }

    bf16x8 aW[2][2][2];
    #pragma unroll
    for (int mi = 0; mi < 2; ++mi) {
        int o = ((mt0 + mi) << 4) + l15;
        #pragma unroll
        for (int ks = 0; ks < 2; ++ks) {
            size_t gg = ((size_t)o << 6) + (ks << 5) + (l4 << 3);
            aW[mi][ks][0] = *(const bf16x8*)(Wch + gg);
            aW[mi][ks][1] = *(const bf16x8*)(Wcl + gg);
        }
    }
    float bias[2][4];
    #pragma unroll
    for (int mi = 0; mi < 2; ++mi)
        #pragma unroll
        for (int r = 0; r < 4; ++r)
            bias[mi][r] = bcv[((mt0 + mi) << 4) + (l4 << 2) + r];

    #pragma unroll
    for (int hh = 0; hh < 4; ++hh) {
        const int h = (ht << 2) + hh;
        const int cur = hh & 1, nxt = cur ^ 1;

        bf16x8 zH[2], zL[2];
        #pragma unroll
        for (int mi = 0; mi < 2; ++mi) {
            int o = ((mt0 + mi) << 4) + l15;
            size_t gg = ((((size_t)((b << 8) + h) << 6) + o) << 5) + (l4 << 3);
            zH[mi] = *(const bf16x8*)(Abh + gg);
            zL[mi] = *(const bf16x8*)(Abl + gg);
        }

        bf16x8 hb[2], lb[2];
        split8(g[cur][0], hb[0], lb[0]);
        split8(g[cur][1], hb[1], lb[1]);

        __syncthreads();
        #pragma unroll
        for (int i = 0; i < 2; ++i) {
            int bidx = (cb0 + (i << 2)) ^ (wloc & 7);
            *(bf16x8*)(&Xh[0][0] + (wloc << 7) + (bidx << 3)) = hb[i];
            *(bf16x8*)(&Xl[0][0] + (wloc << 7) + (bidx << 3)) = lb[i];
        }
        __syncthreads();

        if (hh < 3) {
            #pragma unroll
            for (int i = 0; i < 2; ++i) {
                const float* xpc = xb + ((size_t)(cb0 + (i << 2)) << 19) + ((hh + 1) << 8);
                #pragma unroll
                for (int j = 0; j < 8; ++j) g[nxt][i][j] = xpc[(size_t)j << 16];
            }
        }

        f32x4 acc[2][2];
        #pragma unroll
        for (int mi = 0; mi < 2; ++mi)
            #pragma unroll
            for (int ni = 0; ni < 2; ++ni)
                acc[mi][ni] = (f32x4){0.f, 0.f, 0.f, 0.f};

        #pragma unroll
        for (int ks = 0; ks < 3; ++ks) {
            bf16x8 bh[2], bl[2];
            #pragma unroll
            for (int ni = 0; ni < 2; ++ni) {
                int w = ((nt0 + ni) << 4) + l15;
                int bidx = ((ks << 2) + l4) ^ (w & 7);
                bh[ni] = *(const bf16x8*)(&Xh[0][0] + (w << 7) + (bidx << 3));
                bl[ni] = *(const bf16x8*)(&Xl[0][0] + (w << 7) + (bidx << 3));
            }
            #pragma unroll
            for (int mi = 0; mi < 2; ++mi) {
                bf16x8 ah_ = (ks < 2) ? aW[mi][ks][0] : zH[mi];
                bf16x8 al_ = (ks < 2) ? aW[mi][ks][1] : zL[mi];
                #pragma unroll
                for (int ni = 0; ni < 2; ++ni) {
                    acc[mi][ni] = __builtin_amdgcn_mfma_f32_16x16x32_bf16(ah_, bh[ni], acc[mi][ni], 0, 0, 0);
                    acc[mi][ni] = __builtin_amdgcn_mfma_f32_16x16x32_bf16(ah_, bl[ni], acc[mi][ni], 0, 0, 0);
                    acc[mi][ni] = __builtin_amdgcn_mfma_f32_16x16x32_bf16(al_, bh[ni], acc[mi][ni], 0, 0, 0);
                }
            }
        }

        #pragma unroll
        for (int mi = 0; mi < 2; ++mi) {
            #pragma unroll
            for (int ni = 0; ni < 2; ++ni) {
                int wg = w0 + ((nt0 + ni) << 4) + l15;
                #pragma unroll
                for (int r = 0; r < 4; ++r) {
                    int o = ((mt0 + mi) << 4) + (l4 << 2) + r;
                    float v = acc[mi][ni][r] + bias[mi][r];
                    out[((size_t)((b << 6) + o) << 16) + ((size_t)h << 8) + wg] = gelu_f(v);
                }
            }
        }
    }
}

extern "C" void kernel_launch(void* const* d_in, const int* in_sizes, int n_in,
                              void* d_out, int out_size, void* d_ws, size_t ws_size,
                              hipStream_t stream) {
    const float* x   = (const float*)d_in[0];
    const float* Wc  = (const float*)d_in[1];
    const float* bcv = (const float*)d_in[2];
    const float* w1r = (const float*)d_in[3];
    const float* w1i = (const float*)d_in[4];
    const float* w2r = (const float*)d_in[5];
    const float* w2i = (const float*)d_in[6];
    float* out = (float*)d_out;

    char* wsb = (char*)d_ws;
    ushort* Abh = (ushort*)wsb;
    ushort* Abl = (ushort*)(wsb + 16777216);
    float2* Xw  = (float2*)wsb;
    float2* XhT = (float2*)(wsb + 33554432);
    float2* S   = (float2*)(wsb + 37748736);
    ushort* Tkh = (ushort*)(wsb + 37748736);          // aliases S head; Tk dead before k_modes
    ushort* Tkl = (ushort*)(wsb + 37748736 + 16384);
    ushort* Wch = (ushort*)(wsb + 41943040);
    ushort* Wcl = (ushort*)(wsb + 41951232);
    ushort* Tgh = (ushort*)(wsb + 41959424);
    ushort* Tgl = (ushort*)(wsb + 41975808);

    k_prep <<<  80, 256, 0, stream>>>(Wc, Wch, Wcl, Tgh, Tgl, Tkh, Tkl);
    k_dftw <<<8192, 128, 0, stream>>>(x, Tkh, Tkl, Xw);
    k_dfth <<<1024, 256, 0, stream>>>(Xw, XhT);
    k_modes<<< 256, 256, 0, stream>>>(XhT, w1r, w1i, w2r, w2i, S);
    k_invh <<<1024, 256, 0, stream>>>(S, Abh, Abl);
    k_final<<<4096, 256, 0, stream>>>(x, Wch, Wcl, Tgh, Tgl, Abh, Abl, bcv, out);
}